// Round 1
// baseline (159.026 us; speedup 1.0000x reference)
//
#include <hip/hip_runtime.h>

#define Bc 8
#define Tc 8
#define Cc 32
#define Hc 16
#define Wc 28
#define NHc 4
#define DKc 8
#define HWc (Hc*Wc)                  // 448
#define INV_SCALE 0.35355339059327373f
#define LN_EPSc 1e-5f

// ---------------------------------------------------------------------------
// Kernel 1: QKV projection + fused LayerNorm of q.
// grid = B*T*NH = 256 blocks, 448 threads (one per (h,w)).
// Layouts: K,V -> (bh, t, hw, dk)   (s-slice contiguous for LDS staging)
//          Q   -> (bh, hw, t, dk)   (t fastest -> coalesced in attn kernel)
// ---------------------------------------------------------------------------
__global__ __launch_bounds__(448) void qkv_ln_kernel(
    const float* __restrict__ first, const float* __restrict__ x,
    const float* __restrict__ Wq, const float* __restrict__ Wk,
    const float* __restrict__ Wv,
    const float* __restrict__ gamma, const float* __restrict__ beta,
    float* __restrict__ Q, float* __restrict__ K, float* __restrict__ V)
{
    int blk  = blockIdx.x;           // (b*T + t)*NH + head
    int head = blk % NHc;
    int bt   = blk / NHc;            // b*T + t
    int t    = bt % Tc;
    int b    = bt / Tc;
    int tid  = threadIdx.x;          // h*W + w

    const float* fp = first + (size_t)bt * Cc * HWc + tid;
    const float* xp = x     + (size_t)bt * Cc * HWc + tid;
    float fv[Cc], xv[Cc];
#pragma unroll
    for (int c = 0; c < Cc; ++c) { fv[c] = fp[c*HWc]; xv[c] = xp[c*HWc]; }

    float qv[DKc], kv[DKc], vv[DKc];
#pragma unroll
    for (int dk = 0; dk < DKc; ++dk) {
        int o = head*DKc + dk;       // lane-uniform -> scalar loads of weights
        float aq = 0.f, ak = 0.f, av = 0.f;
#pragma unroll
        for (int c = 0; c < Cc; ++c) {
            aq = fmaf(Wq[o*Cc+c], fv[c], aq);
            ak = fmaf(Wk[o*Cc+c], xv[c], ak);
            av = fmaf(Wv[o*Cc+c], xv[c], av);
        }
        qv[dk] = aq; kv[dk] = ak; vv[dk] = av;
    }

    int bh = b*NHc + head;
    float* kp = K + (((size_t)bh*Tc + t)*HWc + tid)*DKc;
    float* vp = V + (((size_t)bh*Tc + t)*HWc + tid)*DKc;
    *(float4*)(kp)   = make_float4(kv[0],kv[1],kv[2],kv[3]);
    *(float4*)(kp+4) = make_float4(kv[4],kv[5],kv[6],kv[7]);
    *(float4*)(vp)   = make_float4(vv[0],vv[1],vv[2],vv[3]);
    *(float4*)(vp+4) = make_float4(vv[4],vv[5],vv[6],vv[7]);

    // LayerNorm over (DK,H,W) = 3584 values for this (b,t,head)
    float s1 = 0.f, s2 = 0.f;
#pragma unroll
    for (int dk = 0; dk < DKc; ++dk) { s1 += qv[dk]; s2 += qv[dk]*qv[dk]; }
#pragma unroll
    for (int off = 32; off >= 1; off >>= 1) {
        s1 += __shfl_down(s1, off, 64);
        s2 += __shfl_down(s2, off, 64);
    }
    __shared__ float r1[8], r2[8];
    int wid = tid >> 6, lane = tid & 63;
    if (lane == 0) { r1[wid] = s1; r2[wid] = s2; }
    __syncthreads();
    float S1 = 0.f, S2 = 0.f;
#pragma unroll
    for (int wv2 = 0; wv2 < 7; ++wv2) { S1 += r1[wv2]; S2 += r2[wv2]; }
    const float invN = 1.f / (float)(DKc * HWc);
    float mu   = S1 * invN;
    float var  = S2 * invN - mu*mu;
    float rstd = rsqrtf(var + LN_EPSc);

    float qn[DKc];
#pragma unroll
    for (int dk = 0; dk < DKc; ++dk) {
        float gg = gamma[dk*HWc + tid];
        float bb = beta [dk*HWc + tid];
        qn[dk] = (qv[dk] - mu) * rstd * gg + bb;
    }
    float* qp = Q + (((size_t)bh*HWc + tid)*Tc + t)*DKc;
    *(float4*)(qp)   = make_float4(qn[0],qn[1],qn[2],qn[3]);
    *(float4*)(qp+4) = make_float4(qn[4],qn[5],qn[6],qn[7]);
}

// ---------------------------------------------------------------------------
// Kernel 2: dilated neighborhood space-time attention.
// grid = B*NH*(H/2) = 256 blocks, 448 threads.
// Thread layout: tid = q8*8 + t  (8 t-lanes share one (h,w) -> LDS broadcast).
// K_s/V_s staged to LDS per timestep s (14336 B each).
// Tout = sum over valid (offset,s) of (q·k * INV_SCALE) * v   (NO softmax!)
// Mprob = 1 / sum exp(a - a_max)  (max softmax prob per query per head)
// ---------------------------------------------------------------------------
__global__ __launch_bounds__(448) void attn_kernel(
    const float* __restrict__ Q, const float* __restrict__ K,
    const float* __restrict__ V,
    float* __restrict__ Tout, float* __restrict__ Mprob)
{
    int blk   = blockIdx.x;          // bh*(H/2) + hpair
    int hpair = blk % (Hc/2);
    int bh    = blk / (Hc/2);
    int head  = bh % NHc;
    int dil   = 2*head + 1;          // {1,3,5,7}

    int tid = threadIdx.x;
    int t   = tid & 7;
    int q8  = tid >> 3;              // 0..55
    int w   = q8 % Wc;
    int h   = hpair*2 + q8 / Wc;

    __shared__ float sK[HWc*DKc];
    __shared__ float sV[HWc*DKc];

    const float* qp = Q + (((size_t)bh*HWc + h*Wc + w)*Tc + t)*DKc;
    float4 q0 = *(const float4*)qp;
    float4 q1 = *(const float4*)(qp+4);

    float4 a0 = make_float4(0.f,0.f,0.f,0.f);
    float4 a1 = make_float4(0.f,0.f,0.f,0.f);
    float m = -1e30f, l = 0.f;

    for (int s = 0; s < Tc; ++s) {
        __syncthreads();
        const float* kp = K + ((size_t)bh*Tc + s)*HWc*DKc;
        const float* vp = V + ((size_t)bh*Tc + s)*HWc*DKc;
        *(float4*)(sK + tid*8)     = *(const float4*)(kp + tid*8);
        *(float4*)(sK + tid*8 + 4) = *(const float4*)(kp + tid*8 + 4);
        *(float4*)(sV + tid*8)     = *(const float4*)(vp + tid*8);
        *(float4*)(sV + tid*8 + 4) = *(const float4*)(vp + tid*8 + 4);
        __syncthreads();

        for (int dy = -3; dy <= 3; ++dy) {
            int hh = h + dy*dil;
            if ((unsigned)hh >= (unsigned)Hc) continue;
            const float* kr = sK + hh*Wc*DKc;
            const float* vr = sV + hh*Wc*DKc;
#pragma unroll
            for (int dx = -3; dx <= 3; ++dx) {
                int ww = w + dx*dil;
                if ((unsigned)ww < (unsigned)Wc) {
                    const float* kk = kr + ww*DKc;
                    float4 k0 = *(const float4*)kk;
                    float4 k1 = *(const float4*)(kk+4);
                    float sc = (q0.x*k0.x + q0.y*k0.y + q0.z*k0.z + q0.w*k0.w +
                                q1.x*k1.x + q1.y*k1.y + q1.z*k1.z + q1.w*k1.w)
                               * INV_SCALE;
                    float mn = fmaxf(m, sc);
                    l = l*__expf(m - mn) + __expf(sc - mn);
                    m = mn;
                    const float* vvp = vr + ww*DKc;
                    float4 v0 = *(const float4*)vvp;
                    float4 v1 = *(const float4*)(vvp+4);
                    a0.x = fmaf(sc, v0.x, a0.x);
                    a0.y = fmaf(sc, v0.y, a0.y);
                    a0.z = fmaf(sc, v0.z, a0.z);
                    a0.w = fmaf(sc, v0.w, a0.w);
                    a1.x = fmaf(sc, v1.x, a1.x);
                    a1.y = fmaf(sc, v1.y, a1.y);
                    a1.z = fmaf(sc, v1.z, a1.z);
                    a1.w = fmaf(sc, v1.w, a1.w);
                }
            }
        }
    }

    float* op = Tout + (((size_t)bh*HWc + h*Wc + w)*Tc + t)*DKc;
    *(float4*)op     = a0;
    *(float4*)(op+4) = a1;
    Mprob[((size_t)bh*Tc + t)*HWc + h*Wc + w] = 1.f / l;
}

// ---------------------------------------------------------------------------
// Kernel 3: output projection: out = (M_T @ Wo^T) * M_S
// grid = B*T*4 = 256 blocks (4 output-channel groups), 448 threads.
// ---------------------------------------------------------------------------
__global__ __launch_bounds__(448) void outproj_kernel(
    const float* __restrict__ Tout, const float* __restrict__ Mprob,
    const float* __restrict__ Wo, float* __restrict__ out)
{
    int blk = blockIdx.x;            // bt*4 + og
    int og  = blk % 4;
    int bt  = blk / 4;
    int b   = bt / Tc, t = bt % Tc;
    int tid = threadIdx.x;           // h*W + w

    float mv[Cc];
    float MS = 0.f;
#pragma unroll
    for (int head = 0; head < NHc; ++head) {
        int bh = b*NHc + head;
        const float* tp = Tout + (((size_t)bh*HWc + tid)*Tc + t)*DKc;
        float4 u0 = *(const float4*)tp;
        float4 u1 = *(const float4*)(tp+4);
        mv[head*8+0]=u0.x; mv[head*8+1]=u0.y; mv[head*8+2]=u0.z; mv[head*8+3]=u0.w;
        mv[head*8+4]=u1.x; mv[head*8+5]=u1.y; mv[head*8+6]=u1.z; mv[head*8+7]=u1.w;
        MS = fmaxf(MS, Mprob[((size_t)bh*Tc + t)*HWc + tid]);
    }
#pragma unroll
    for (int i = 0; i < 8; ++i) {
        int o = og*8 + i;
        float acc = 0.f;
#pragma unroll
        for (int c = 0; c < Cc; ++c) acc = fmaf(Wo[o*Cc+c], mv[c], acc);
        out[((size_t)bt*Cc + o)*HWc + tid] = acc * MS;
    }
}

// ---------------------------------------------------------------------------
extern "C" void kernel_launch(void* const* d_in, const int* in_sizes, int n_in,
                              void* d_out, int out_size, void* d_ws, size_t ws_size,
                              hipStream_t stream) {
    const float* first = (const float*)d_in[0];
    const float* x     = (const float*)d_in[1];
    const float* Wq    = (const float*)d_in[2];
    const float* Wk    = (const float*)d_in[3];
    const float* Wv    = (const float*)d_in[4];
    const float* Wo    = (const float*)d_in[5];
    const float* g     = (const float*)d_in[6];
    const float* bta   = (const float*)d_in[7];
    float* out = (float*)d_out;

    float* ws  = (float*)d_ws;
    const size_t N5 = (size_t)Bc*NHc*Tc*HWc*DKc;   // 917504
    float* Q  = ws;
    float* K  = ws + N5;
    float* V  = ws + 2*N5;
    float* Tt = ws + 3*N5;
    float* Mp = ws + 4*N5;                          // 114688 floats

    qkv_ln_kernel <<<Bc*Tc*NHc,      448, 0, stream>>>(first, x, Wq, Wk, Wv, g, bta, Q, K, V);
    attn_kernel   <<<Bc*NHc*(Hc/2),  448, 0, stream>>>(Q, K, V, Tt, Mp);
    outproj_kernel<<<Bc*Tc*4,        448, 0, stream>>>(Tt, Mp, Wo, out);
}